// Round 5
// baseline (106.106 us; speedup 1.0000x reference)
//
#include <hip/hip_runtime.h>
#include <math.h>

// Problem constants (fixed shapes from setup_inputs)
#define B_    8
#define C_    4
#define H_    256
#define W_    256
#define NCLS  3                      // classes 1..3
#define NROWS (NCLS * B_ * H_)       // 6144 rows for horizontal pass
#define HBLOCKS (NROWS / 4)          // 1536 horiz blocks; 1 row per wave
#define NSLOT 16                     // scattered fp64 accumulator slots
#define BIGVAL (1 << 26)             // pad value, never wins the min

// ---------------------------------------------------------------------------
// Kernel 1: vertical 1D distance g = min(d_up, d_down, 512) via bitmask scan.
// Block = (class, b, w-tile of 64). 4 waves = 4 h-chunks of 64 rows.
// Thread (hc, lane): builds u64 bg bitmask for its 64 rows of column w
// (coalesced row loads), then per row derives d_up via clz on the prefix
// bits and d_down via ctz on the suffix bits; cross-chunk carries exchanged
// through a 4-entry LDS summary per column. Matches ref semantics:
// no-bg-above => d_up = h+512 (clamped 512); g = min(du, dd, BIG=512).
// Also zero-inits the accumulator slots + completion counter for kernel 2
// (visible via stream-order kernel-boundary release/acquire).
// ---------------------------------------------------------------------------
__global__ __launch_bounds__(256) void vert_g_kernel(const int* __restrict__ mask,
                                                     unsigned short* __restrict__ gbuf,
                                                     double* __restrict__ acc,
                                                     unsigned int* __restrict__ counter) {
    if (blockIdx.x == 0) {
        if (threadIdx.x < NSLOT) acc[threadIdx.x * 8] = 0.0;   // 64B-spaced slots
        if (threadIdx.x == NSLOT) *counter = 0u;
    }

    const int lane = threadIdx.x & 63;
    const int hc   = threadIdx.x >> 6;          // h-chunk 0..3
    const int blk  = blockIdx.x;                // 0..95
    const int wt   = blk & 3;
    const int b    = (blk >> 2) & 7;
    const int c_i  = blk >> 5;                  // 0..2
    const int cls  = c_i + 1;
    const int w    = (wt << 6) + lane;

    __shared__ int last_sh[4][64];              // highest bg row per chunk (or -512)
    __shared__ int first_sh[4][64];             // lowest bg row per chunk (or big)

    const int* mptr = mask + (b << 16) + (hc << 14) + w;   // row hc*64, col w
    unsigned long long bg = 0ull;
    #pragma unroll 8
    for (int i = 0; i < 64; ++i) {
        int m = mptr[i << 8];
        bg |= (unsigned long long)(m != cls) << i;
    }
    last_sh[hc][lane]  = bg ? ((hc << 6) + 63 - __builtin_clzll(bg)) : -512;
    first_sh[hc][lane] = bg ? ((hc << 6) + __builtin_ctzll(bg)) : (1 << 20);
    __syncthreads();

    int carry_up = -512;                        // last bg row in chunks above
    #pragma unroll
    for (int k = 0; k < 4; ++k)
        if (k < hc) carry_up = max(carry_up, last_sh[k][lane]);
    int carry_dn = 1 << 20;                     // first bg row in chunks below
    #pragma unroll
    for (int k = 0; k < 4; ++k)
        if (k > hc) carry_dn = min(carry_dn, first_sh[k][lane]);

    unsigned short* gout = gbuf + (((c_i << 3) + b) << 16) + (hc << 14) + w;
    #pragma unroll 4
    for (int i = 0; i < 64; ++i) {
        int h = (hc << 6) + i;
        unsigned long long le = bg & (~0ull >> (63 - i));   // bg bits at rows <= h
        int last = le ? ((hc << 6) + 63 - __builtin_clzll(le)) : carry_up;
        int du = h - last;
        unsigned long long ge = bg >> i;                    // bg bits at rows >= h
        int first = ge ? (h + __builtin_ctzll(ge)) : carry_dn;
        int dd = first - h;
        int g = min(min(du, dd), 512);
        gout[i << 8] = (unsigned short)g;
    }
}

// ---------------------------------------------------------------------------
// Kernel 2: exact horizontal lower-envelope + fused loss + finalize.
// R3-proven shape: 1536 blocks x 4 waves, ONE row per wave (no inner barrier
// loop, 6/CU occupancy). Lane owns x = 4*lane + j (ushort4/float4/int4).
// Exactness: D2[x] <= g2[x]; an x' improves only if |x-x'| <= g[x]-1 <=
// rowmax(g)-1 = R, so the radius-R windowed search is exact; every candidate
// is a genuine upper bound. Brute-force fallback for large R.
// Block partial -> fp64 atomicAdd scattered over 16 cache-line-spaced slots;
// last-arriving block sums slots, normalizes, writes the scalar.
// ---------------------------------------------------------------------------
__global__ __launch_bounds__(256) void horiz_kernel(const unsigned short* __restrict__ gbuf,
                                                    const float* __restrict__ pred,
                                                    double* __restrict__ acc,
                                                    unsigned int* __restrict__ counter,
                                                    float* __restrict__ out) {
    const int lane = threadIdx.x & 63;
    const int wv   = threadIdx.x >> 6;
    const int row  = blockIdx.x * 4 + wv;       // 0..6143
    const int c_i  = row >> 11;
    const int b    = (row >> 8) & 7;
    const int h    = row & 255;
    const int cls  = c_i + 1;

    __shared__ __align__(16) int ext[4][512];   // per-wave padded g2 row: x = i-128
    __shared__ double wsum[4];

    const int x0 = lane << 2;
    ushort4 gv = *(const ushort4*)(gbuf + row * 256 + x0);
    int g0 = gv.x, g1 = gv.y, g2v = gv.z, g3 = gv.w;
    int q0 = g0 * g0, q1 = g1 * g1, q2 = g2v * g2v, q3 = g3 * g3;
    *(int4*)&ext[wv][128 + x0] = make_int4(q0, q1, q2, q3);
    // pads: [0,128) and [384,512)
    ext[wv][lane]       = BIGVAL;
    ext[wv][64 + lane]  = BIGVAL;
    ext[wv][384 + lane] = BIGVAL;
    ext[wv][448 + lane] = BIGVAL;
    __syncthreads();

    // wave max of g -> window radius
    int gm = max(max(g0, g1), max(g2v, g3));
    #pragma unroll
    for (int off = 32; off > 0; off >>= 1) gm = max(gm, __shfl_xor(gm, off, 64));
    const int R = gm - 1;

    int D2[4] = { q0, q1, q2, q3 };
    const int* e = &ext[wv][128];

    if (R >= 120) {
        // brute force over all source columns (rare)
        for (int xp = 0; xp < 256; ++xp) {
            int s = e[xp];
            #pragma unroll
            for (int j = 0; j < 4; ++j) {
                int d = (x0 + j) - xp;
                int cand = s + d * d;
                D2[j] = (cand < D2[j]) ? cand : D2[j];
            }
        }
    } else if (R >= 1) {
        for (int o = 1; o <= R; ++o) {
            int oo = o * o;
            #pragma unroll
            for (int j = 0; j < 4; ++j) {
                int xj = x0 + j;
                int c1 = e[xj + o];
                int c2 = e[xj - o];
                int cm = (c1 < c2) ? c1 : c2;
                int cand = cm + oo;
                D2[j] = (cand < D2[j]) ? cand : D2[j];
            }
        }
    }
    // (R <= 0: all background in window -> D2 = g2)

    // fused loss terms in fp64
    const float* prow = pred + ((((b << 2) + cls) << 8) + h) * 256;
    float4 pv = *(const float4*)(prow + x0);
    double sum = sqrt((double)D2[0]) * (double)pv.x
               + sqrt((double)D2[1]) * (double)pv.y
               + sqrt((double)D2[2]) * (double)pv.z
               + sqrt((double)D2[3]) * (double)pv.w;
    #pragma unroll
    for (int off = 32; off > 0; off >>= 1) sum += __shfl_xor(sum, off, 64);
    if (lane == 0) wsum[wv] = sum;
    __syncthreads();
    if (threadIdx.x == 0) {
        double total = wsum[0] + wsum[1] + wsum[2] + wsum[3];
        atomicAdd(&acc[(blockIdx.x & (NSLOT - 1)) * 8], total);   // device-scope
        __threadfence();
        unsigned int old = atomicAdd(counter, 1u);
        if (old == (unsigned int)(HBLOCKS - 1)) {
            double s = 0.0;
            #pragma unroll
            for (int i = 0; i < NSLOT; ++i)
                s += atomicAdd(&acc[i * 8], 0.0);   // coherent reads
            double nd = sqrt(131072.0) + 1e-6;      // sqrt(H^2+W^2)+1e-6
            double norm = (double)(float)nd;        // ref casts to float32
            out[0] = (float)(s / norm / ((double)NCLS * (double)(B_ * H_ * W_)));
        }
    }
}

extern "C" void kernel_launch(void* const* d_in, const int* in_sizes, int n_in,
                              void* d_out, int out_size, void* d_ws, size_t ws_size,
                              hipStream_t stream) {
    const float* pred = (const float*)d_in[0];   // [8,4,256,256] f32
    const int*   mask = (const int*)d_in[1];     // [8,256,256] int
    float* out = (float*)d_out;

    char* ws = (char*)d_ws;
    double* acc = (double*)ws;                                   // 16 slots, 64B-spaced
    unsigned int* counter = (unsigned int*)(ws + 4096);          // 4 B
    unsigned short* gbuf = (unsigned short*)(ws + 16384);        // 3 MB

    vert_g_kernel<<<NCLS * 8 * 4, 256, 0, stream>>>(mask, gbuf, acc, counter);
    horiz_kernel<<<HBLOCKS, 256, 0, stream>>>(gbuf, pred, acc, counter, out);
}

// Round 7
// 68.307 us; speedup vs baseline: 1.5534x; 1.5534x over previous
//
#include <hip/hip_runtime.h>
#include <math.h>

// Problem constants (fixed shapes from setup_inputs)
#define B_    8
#define C_    4
#define H_    256
#define W_    256
#define NCLS  3                      // classes 1..3
#define NROWS (NCLS * B_ * H_)       // 6144 rows for horizontal pass
#define BIGVAL (1 << 26)             // pad value, never wins the min

// ---------------------------------------------------------------------------
// Kernel 1: vertical 1D distance g = min(d_up, d_down, 512) via bitmask scan.
// Block = (class, b, w-tile of 64). 4 waves = 4 h-chunks of 64 rows.
// Thread (hc, lane): fully-unrolled 64 coalesced row loads into registers
// (max memory-level parallelism), builds u64 bg bitmask, then per row derives
// d_up via clz on prefix bits and d_down via ctz on suffix bits; cross-chunk
// carries via 4-entry LDS summaries. Matches ref semantics: no-bg-above =>
// d_up = h+512 (clamped 512); g = min(du, dd, BIG=512).
// ---------------------------------------------------------------------------
__global__ __launch_bounds__(256) void vert_g_kernel(const int* __restrict__ mask,
                                                     unsigned short* __restrict__ gbuf) {
    const int lane = threadIdx.x & 63;
    const int hc   = threadIdx.x >> 6;          // h-chunk 0..3
    const int blk  = blockIdx.x;                // 0..95
    const int wt   = blk & 3;
    const int b    = (blk >> 2) & 7;
    const int c_i  = blk >> 5;                  // 0..2
    const int cls  = c_i + 1;
    const int w    = (wt << 6) + lane;

    __shared__ int last_sh[4][64];              // highest bg row per chunk (or -512)
    __shared__ int first_sh[4][64];             // lowest bg row per chunk (or big)

    const int* mptr = mask + (b << 16) + (hc << 14) + w;   // row hc*64, col w
    int m[64];
    #pragma unroll
    for (int i = 0; i < 64; ++i) m[i] = mptr[i << 8];      // all independent
    unsigned long long bg = 0ull;
    #pragma unroll
    for (int i = 0; i < 64; ++i)
        bg |= (unsigned long long)(m[i] != cls) << i;

    last_sh[hc][lane]  = bg ? ((hc << 6) + 63 - __builtin_clzll(bg)) : -512;
    first_sh[hc][lane] = bg ? ((hc << 6) + __builtin_ctzll(bg)) : (1 << 20);
    __syncthreads();

    int carry_up = -512;                        // last bg row in chunks above
    #pragma unroll
    for (int k = 0; k < 4; ++k)
        if (k < hc) carry_up = max(carry_up, last_sh[k][lane]);
    int carry_dn = 1 << 20;                     // first bg row in chunks below
    #pragma unroll
    for (int k = 0; k < 4; ++k)
        if (k > hc) carry_dn = min(carry_dn, first_sh[k][lane]);

    unsigned short* gout = gbuf + (((c_i << 3) + b) << 16) + (hc << 14) + w;
    #pragma unroll 4
    for (int i = 0; i < 64; ++i) {
        int h = (hc << 6) + i;
        unsigned long long le = bg & (~0ull >> (63 - i));   // bg bits at rows <= h
        int last = le ? ((hc << 6) + 63 - __builtin_clzll(le)) : carry_up;
        int du = h - last;
        unsigned long long ge = bg >> i;                    // bg bits at rows >= h
        int first = ge ? (h + __builtin_ctzll(ge)) : carry_dn;
        int dd = first - h;
        int g = min(min(du, dd), 512);
        gout[i << 8] = (unsigned short)g;
    }
}

// ---------------------------------------------------------------------------
// Kernel 2: exact horizontal lower-envelope + fused loss partial.
// 1536 blocks x 4 waves, ONE row per wave. NO __syncthreads: each wave uses
// only its own ext[wv] slice; wave-internal LDS ordering (lgkmcnt) suffices.
// Both global loads (pred, gbuf) issued up front to overlap latencies.
// Exactness: D2[x] <= g2[x]; an x' improves only if |x-x'| <= g[x]-1 <=
// rowmax(g)-1 = R, so the radius-R windowed search is exact; every candidate
// is a genuine upper bound. Brute-force fallback for large R.
// Each wave stores its own fp64 partial (deterministic, no atomics/fences).
// ---------------------------------------------------------------------------
__global__ __launch_bounds__(256) void horiz_kernel(const unsigned short* __restrict__ gbuf,
                                                    const float* __restrict__ pred,
                                                    double* __restrict__ acc) {
    const int lane = threadIdx.x & 63;
    const int wv   = threadIdx.x >> 6;
    const int row  = blockIdx.x * 4 + wv;       // 0..6143
    const int c_i  = row >> 11;
    const int b    = (row >> 8) & 7;
    const int h    = row & 255;
    const int cls  = c_i + 1;

    __shared__ __align__(16) int ext[4][512];   // per-wave padded g2 row: x = i-128

    const int x0 = lane << 2;
    // issue both independent global loads immediately (overlapped latencies)
    const float* prow = pred + ((((b << 2) + cls) << 8) + h) * 256;
    float4 pv = *(const float4*)(prow + x0);
    ushort4 gv = *(const ushort4*)(gbuf + row * 256 + x0);

    int g0 = gv.x, g1 = gv.y, g2v = gv.z, g3 = gv.w;
    int q0 = g0 * g0, q1 = g1 * g1, q2 = g2v * g2v, q3 = g3 * g3;
    *(int4*)&ext[wv][128 + x0] = make_int4(q0, q1, q2, q3);
    // pads: [0,128) and [384,512)
    ext[wv][lane]       = BIGVAL;
    ext[wv][64 + lane]  = BIGVAL;
    ext[wv][384 + lane] = BIGVAL;
    ext[wv][448 + lane] = BIGVAL;
    // no barrier: single-wave ownership of ext[wv]; lgkmcnt orders ds ops

    // wave max of g -> window radius
    int gm = max(max(g0, g1), max(g2v, g3));
    #pragma unroll
    for (int off = 32; off > 0; off >>= 1) gm = max(gm, __shfl_xor(gm, off, 64));
    const int R = gm - 1;

    int D2[4] = { q0, q1, q2, q3 };
    const int* e = &ext[wv][128];

    if (R >= 120) {
        // brute force over all source columns (rare)
        for (int xp = 0; xp < 256; ++xp) {
            int s = e[xp];
            #pragma unroll
            for (int j = 0; j < 4; ++j) {
                int d = (x0 + j) - xp;
                int cand = s + d * d;
                D2[j] = (cand < D2[j]) ? cand : D2[j];
            }
        }
    } else if (R >= 1) {
        for (int o = 1; o <= R; ++o) {
            int oo = o * o;
            #pragma unroll
            for (int j = 0; j < 4; ++j) {
                int xj = x0 + j;
                int c1 = e[xj + o];
                int c2 = e[xj - o];
                int cm = (c1 < c2) ? c1 : c2;
                int cand = cm + oo;
                D2[j] = (cand < D2[j]) ? cand : D2[j];
            }
        }
    }
    // (R <= 0: all background in window -> D2 = g2)

    // loss terms: f32 sqrt (D2 < 2^24, exact in f32), fp64 accumulate
    double sum = (double)(sqrtf((float)D2[0]) * pv.x)
               + (double)(sqrtf((float)D2[1]) * pv.y)
               + (double)(sqrtf((float)D2[2]) * pv.z)
               + (double)(sqrtf((float)D2[3]) * pv.w);
    #pragma unroll
    for (int off = 32; off > 0; off >>= 1) sum += __shfl_xor(sum, off, 64);
    if (lane == 0) acc[row] = sum;              // plain store, deterministic
}

// ---------------------------------------------------------------------------
// Kernel 3: deterministic final reduction + normalization. 256 threads,
// 24 independent fp64 loads per thread, LDS + shuffle reduce.
// ---------------------------------------------------------------------------
__global__ __launch_bounds__(256) void final_kernel(const double* __restrict__ acc,
                                                    float* __restrict__ out) {
    const int t = threadIdx.x;
    __shared__ double wsum[4];
    double s = 0.0;
    #pragma unroll
    for (int i = 0; i < NROWS / 256; ++i) s += acc[t + i * 256];
    #pragma unroll
    for (int off = 32; off > 0; off >>= 1) s += __shfl_xor(s, off, 64);
    if ((t & 63) == 0) wsum[t >> 6] = s;
    __syncthreads();
    if (t == 0) {
        double total = wsum[0] + wsum[1] + wsum[2] + wsum[3];
        double nd = sqrt(131072.0) + 1e-6;          // sqrt(H^2+W^2)+1e-6
        double norm = (double)(float)nd;            // ref casts to float32
        out[0] = (float)(total / norm / ((double)NCLS * (double)(B_ * H_ * W_)));
    }
}

extern "C" void kernel_launch(void* const* d_in, const int* in_sizes, int n_in,
                              void* d_out, int out_size, void* d_ws, size_t ws_size,
                              hipStream_t stream) {
    const float* pred = (const float*)d_in[0];   // [8,4,256,256] f32
    const int*   mask = (const int*)d_in[1];     // [8,256,256] int
    float* out = (float*)d_out;

    char* ws = (char*)d_ws;
    double* acc = (double*)ws;                                   // 6144 doubles
    unsigned short* gbuf = (unsigned short*)(ws + 65536);        // 3 MB

    vert_g_kernel<<<NCLS * 8 * 4, 256, 0, stream>>>(mask, gbuf);
    horiz_kernel<<<NROWS / 4, 256, 0, stream>>>(gbuf, pred, acc);
    final_kernel<<<1, 256, 0, stream>>>(acc, out);
}